// Round 8
// baseline (1059.601 us; speedup 1.0000x reference)
//
#include <hip/hip_runtime.h>

// ---------------- problem constants ----------------
#define V_CODES 8192
#define D_DIM   256
#define SPATIAL 4096            // 16*16*16
#define M_ROWS  32768           // 8 * 4096
#define NELEM   8388608         // M_ROWS * D_DIM

static constexpr float GAMMA_F = 0.99f;
static constexpr float OMG_F   = (float)(1.0 - 0.99);
static constexpr float EPS_F   = 1e-7f;
static constexpr float VEPS_F  = (float)(8192 * 1e-7);

// output layout (floats), concatenated in reference return order
static constexpr size_t OFF_QUANT = 0;            // 8388608  quant_st
static constexpr size_t OFF_IDX   = 8388608;      // 32768    enc_idx (stored as float)
static constexpr size_t OFF_QDIFF = 8421376;      // 1        quant_diff
static constexpr size_t OFF_NN    = 8421377;      // 8192     new_N
static constexpr size_t OFF_ZAVG  = 8429569;      // 2097152  new_z_avg
static constexpr size_t OFF_W     = 10526721;     // 2097152  new_weight

typedef _Float16 f16x8  __attribute__((ext_vector_type(8)));
typedef _Float16 f16x4  __attribute__((ext_vector_type(4)));
typedef float    f32x4  __attribute__((ext_vector_type(4)));

// async global->LDS, 16B per lane; LDS dest is wave-uniform base + lane*16
#define GLL(gp, lp) __builtin_amdgcn_global_load_lds( \
    (const __attribute__((address_space(1))) unsigned int*)(gp), \
    (__attribute__((address_space(3))) unsigned int*)(lp), 16, 0, 0)

// ---------------- K0c: split W into fp16 hi/lo planes + row norms (fused) ----------------
__global__ void k_split_w(const float* __restrict__ W, _Float16* __restrict__ Wh,
                          _Float16* __restrict__ Wl, float* __restrict__ wnorm) {
    int t = threadIdx.x;
    size_t i8 = ((size_t)blockIdx.x * 256 + t) * 8;
    float4 a = *(const float4*)(W + i8);
    float4 b = *(const float4*)(W + i8 + 4);
    float v[8] = {a.x, a.y, a.z, a.w, b.x, b.y, b.z, b.w};
    f16x8 hi, lo;
    float ns = 0.0f;
    #pragma unroll
    for (int j = 0; j < 8; j++) {
        _Float16 h = (_Float16)v[j];
        hi[j] = h;
        lo[j] = (_Float16)(v[j] - (float)h);
        ns = fmaf(v[j], v[j], ns);
    }
    *(f16x8*)(Wh + i8) = hi;
    *(f16x8*)(Wl + i8) = lo;
    // row norm: 32 threads per 256-elem row (8 elems each); reduce in 32-group
    #pragma unroll
    for (int m = 16; m > 0; m >>= 1) ns += __shfl_xor(ns, m, 64);
    if ((t & 31) == 0) wnorm[blockIdx.x * 8 + (t >> 5)] = ns;
}

// ---------------- K0d: split + transpose X (b,k,sp) -> Xh/Xl (m, k) row-major ----------------
__global__ void k_split_x(const float* __restrict__ X, _Float16* __restrict__ Xh,
                          _Float16* __restrict__ Xl) {
    int bid  = blockIdx.x;            // 1024 blocks
    int lane = threadIdx.x & 63;
    int kg   = (bid & 1) * 4 + (threadIdx.x >> 6);   // 0..7 -> k base kg*32
    int m    = (bid >> 1) * 64 + lane;
    int b  = m >> 12;
    int sp = m & 4095;
    const float* src = X + (size_t)b * (D_DIM * SPATIAL) + (size_t)(kg * 32) * SPATIAL + sp;
    float v[32];
    #pragma unroll
    for (int j = 0; j < 32; j++) v[j] = src[(size_t)j * SPATIAL];   // coalesced across lanes
    _Float16* dh = Xh + (size_t)m * D_DIM + kg * 32;
    _Float16* dl = Xl + (size_t)m * D_DIM + kg * 32;
    #pragma unroll
    for (int c = 0; c < 4; c++) {
        f16x8 hi, lo;
        #pragma unroll
        for (int j = 0; j < 8; j++) {
            float x = v[c * 8 + j];
            _Float16 h = (_Float16)x;
            hi[j] = h;
            lo[j] = (_Float16)(x - (float)h);
        }
        *(f16x8*)(dh + c * 8) = hi;
        *(f16x8*)(dl + c * 8) = lo;
    }
}

// ---------------- K1: MFMA distance GEMM + argmin ----------------
// v9: same proven 2-sync single-buffer schedule as v8 (the only lever that
// has moved the needle is geometry), widened to 256x256 tile, 8 waves
// (512 thr, wave grid 2x4; wave out = 128 rows x 64 cols):
//  - 4096 blocks (was 8192): per-block fixed costs halve again
//  - staged traffic 3.1 -> 2.1 GB (64 KiB feeds 768 MFMAs vs 48 KiB/384)
//  - LDS 64 KiB -> 2 blocks/CU = 16 waves/CU (~50% occ, was 23%): doubles
//    the TLP pool that hides the per-step GLL drain (m114 mechanism)
//  - VGPR: acc 128 (AGPR) + B 32 + A 8/mi + addr ~20 < 256 -> no spill at
//    __launch_bounds__(512,2) (watch WRITE_SIZE for spill regression)
// LDS: 64 subtiles x 1 KiB: Xh 0-15, Xl 16-31, Wh 32-47, Wl 48-63.
// Subtile fragment order: lane l <-> halves [8l,8l+8) = row (l&15),
// k-chunk (l>>4) -> linear GLL dest, conflict-free ds_read_b128.
// Per-output product order (hh, lh, hl) and k-order identical to v8.
__device__ inline unsigned long long packkey(float s, int v) {
    unsigned u = __float_as_uint(s);
    u = (u & 0x80000000u) ? ~u : (u | 0x80000000u);
    return ((unsigned long long)u << 32) | (unsigned)v;
}

__global__ __launch_bounds__(512, 2) void k_mfma_argmin(
        const _Float16* __restrict__ Xh, const _Float16* __restrict__ Xl,
        const _Float16* __restrict__ Wh, const _Float16* __restrict__ Wl,
        const float* __restrict__ wnorm, unsigned long long* __restrict__ best) {
    __shared__ __align__(16) _Float16 lds[32768];   // 64 KiB, single buffer
    const int tid  = threadIdx.x;
    const int wid  = tid >> 6;
    const int lane = tid & 63;
    const int lrow = lane & 15, lq = lane >> 4;
    const int wy = wid >> 2, wx = wid & 3;          // wave out: rows [wy*128,+128), cols [wx*64,+64)
    const int m0 = blockIdx.y * 256;
    const int v0 = blockIdx.x * 256;

    const _Float16* const planes[4] = {Xh, Xl, Wh, Wl};

    // staging: wave wid owns subtiles ss = wid*8 .. wid*8+7
    // ss: plane = ss>>4 (0=Xh 1=Xl 2=Wh 3=Wl), row-chunk = ss&15
    const _Float16* gp[8];
    #pragma unroll
    for (int j = 0; j < 8; ++j) {
        int ss = wid * 8 + j;
        int pl = ss >> 4;
        int ro = ss & 15;
        gp[j] = planes[pl] + (size_t)((pl < 2 ? m0 : v0) + ro * 16 + lrow) * D_DIM + lq * 8;
    }

    f32x4 acc[8][4] = {};

    for (int k0 = 0; k0 < D_DIM; k0 += 32) {
        __syncthreads();                            // prior LDS reads done
        #pragma unroll
        for (int j = 0; j < 8; ++j)
            GLL(gp[j] + k0, &lds[(wid * 8 + j) * 512]);
        __syncthreads();                            // GLL writes visible
        // B fragments for this wave's 64 cols (4 subtiles x 2 planes)
        f16x8 bh[4], bl[4];
        #pragma unroll
        for (int i = 0; i < 4; ++i) {
            bh[i] = *(const f16x8*)&lds[(32 + wx * 4 + i) * 512 + lane * 8];
            bl[i] = *(const f16x8*)&lds[(48 + wx * 4 + i) * 512 + lane * 8];
        }
        #pragma unroll
        for (int mi = 0; mi < 8; ++mi) {
            f16x8 ah = *(const f16x8*)&lds[(     wy * 8 + mi) * 512 + lane * 8];
            f16x8 al = *(const f16x8*)&lds[(16 + wy * 8 + mi) * 512 + lane * 8];
            __builtin_amdgcn_s_setprio(1);
            #pragma unroll
            for (int vi = 0; vi < 4; ++vi) {
                acc[mi][vi] = __builtin_amdgcn_mfma_f32_16x16x32_f16(ah, bh[vi], acc[mi][vi], 0, 0, 0);
                acc[mi][vi] = __builtin_amdgcn_mfma_f32_16x16x32_f16(al, bh[vi], acc[mi][vi], 0, 0, 0);
                acc[mi][vi] = __builtin_amdgcn_mfma_f32_16x16x32_f16(ah, bl[vi], acc[mi][vi], 0, 0, 0);
            }
            __builtin_amdgcn_s_setprio(0);
        }
    }

    float wnv[4];
    #pragma unroll
    for (int vi = 0; vi < 4; ++vi) wnv[vi] = wnorm[v0 + (wx * 4 + vi) * 16 + lrow];

    #pragma unroll
    for (int mi = 0; mi < 8; ++mi) {
        #pragma unroll
        for (int r = 0; r < 4; ++r) {
            unsigned long long k = ~0ull;
            #pragma unroll
            for (int vi = 0; vi < 4; ++vi) {
                int v = v0 + (wx * 4 + vi) * 16 + lrow;
                float s = wnv[vi] - 2.0f * acc[mi][vi][r];
                unsigned long long key = packkey(s, v);
                k = key < k ? key : k;
            }
            #pragma unroll
            for (int msk = 1; msk < 16; msk <<= 1) {
                unsigned long long o = __shfl_xor(k, msk, 64);
                k = o < k ? o : k;
            }
            if (lrow == 0) {
                int m = m0 + wy * 128 + mi * 16 + lq * 4 + r;
                atomicMin(&best[m], k);
            }
        }
    }
}

// ---------------- K2a: extract idx, count per code ----------------
__global__ void k_count(const unsigned long long* __restrict__ best,
                        int* __restrict__ counts, float* __restrict__ out) {
    int m = blockIdx.x * 256 + threadIdx.x;
    int v = (int)(unsigned)(best[m] & 0xFFFFFFFFull);
    atomicAdd(&counts[v], 1);
    out[OFF_IDX + m] = (float)v;
}

// ---------------- K2b: exclusive prefix over 8192 counts ----------------
__global__ void k_prefix(const int* __restrict__ counts, int* __restrict__ offsets,
                         int* __restrict__ cursor) {
    __shared__ int tsum[256];
    int t = threadIdx.x;
    int local[32];
    int s = 0;
    #pragma unroll
    for (int i = 0; i < 32; i++) { local[i] = s; s += counts[t * 32 + i]; }
    tsum[t] = s;
    __syncthreads();
    if (t == 0) {
        int run = 0;
        for (int i = 0; i < 256; i++) { int c = tsum[i]; tsum[i] = run; run += c; }
    }
    __syncthreads();
    int base = tsum[t];
    #pragma unroll
    for (int i = 0; i < 32; i++) {
        int o = base + local[i];
        offsets[t * 32 + i] = o;
        cursor[t * 32 + i]  = o;
    }
}

// ---------------- K2c: fill bins ----------------
__global__ void k_fill(const unsigned long long* __restrict__ best,
                       int* __restrict__ cursor, int* __restrict__ bin) {
    int m = blockIdx.x * 256 + threadIdx.x;
    int v = (int)(unsigned)(best[m] & 0xFFFFFFFFull);
    int pos = atomicAdd(&cursor[v], 1);
    bin[pos] = m;
}

// ---------------- K2d: per-code reduction -> new_N, new_z_avg ----------------
__global__ void k_codes(const _Float16* __restrict__ Xh, const _Float16* __restrict__ Xl,
                        const float* __restrict__ N, const float* __restrict__ zavg,
                        const int* __restrict__ counts, const int* __restrict__ offsets,
                        const int* __restrict__ bin, float* __restrict__ out,
                        float* __restrict__ ws_scal) {
    int v = blockIdx.x;
    int t = threadIdx.x;
    int r4 = t >> 6;          // row class 0..3
    int dg = t & 63;          // d-group: d = dg*4 .. dg*4+3
    int cnt = counts[v];
    int off = offsets[v];
    float s0 = 0.f, s1 = 0.f, s2 = 0.f, s3 = 0.f;
    for (int r = r4; r < cnt; r += 4) {
        int m = bin[off + r];
        f16x4 h = *(const f16x4*)(Xh + (size_t)m * D_DIM + dg * 4);
        f16x4 l = *(const f16x4*)(Xl + (size_t)m * D_DIM + dg * 4);
        s0 += (float)h[0] + (float)l[0];
        s1 += (float)h[1] + (float)l[1];
        s2 += (float)h[2] + (float)l[2];
        s3 += (float)h[3] + (float)l[3];
    }
    __shared__ float red[4][256];
    *(float4*)&red[r4][dg * 4] = make_float4(s0, s1, s2, s3);
    __syncthreads();
    float tot = red[0][t] + red[1][t] + red[2][t] + red[3][t];
    out[OFF_ZAVG + (size_t)v * D_DIM + t] = GAMMA_F * zavg[(size_t)v * D_DIM + t] + OMG_F * tot;
    if (t == 0) {
        float nn = GAMMA_F * N[v] + OMG_F * (float)cnt;
        out[OFF_NN + v] = nn;
        atomicAdd(&ws_scal[1], nn);
    }
}

// ---------------- K3: quant_st + quant_diff (float4 along sp) ----------------
__global__ void k_quant(const float* __restrict__ X, const float* __restrict__ W,
                        const unsigned long long* __restrict__ best, float* __restrict__ out,
                        float* __restrict__ ws_scal) {
    int e4 = blockIdx.x * 256 + threadIdx.x;    // element/4 in (b, d, sp) order
    int e  = e4 * 4;
    int sp = e & 4095;
    int bd = e >> 12;
    int d  = bd & 255;
    int b  = bd >> 8;
    int mb = b * SPATIAL + sp;
    float4 x4 = *(const float4*)(X + e);
    float q[4];
    float p = 0.0f;
    #pragma unroll
    for (int j = 0; j < 4; j++) {
        int v = (int)(unsigned)(best[mb + j] & 0xFFFFFFFFull);
        float wv = W[(size_t)v * D_DIM + d];
        float xv = (j == 0) ? x4.x : (j == 1) ? x4.y : (j == 2) ? x4.z : x4.w;
        q[j] = (wv - xv) + xv;                 // straight-through
        float df = xv - wv;
        p = fmaf(df, df, p);
    }
    *(float4*)(out + OFF_QUANT + e) = make_float4(q[0], q[1], q[2], q[3]);
    // block-reduce p -> one atomic
    #pragma unroll
    for (int msk = 32; msk > 0; msk >>= 1) p += __shfl_xor(p, msk, 64);
    __shared__ float red[4];
    int lane = threadIdx.x & 63, w = threadIdx.x >> 6;
    if (lane == 0) red[w] = p;
    __syncthreads();
    if (threadIdx.x == 0)
        atomicAdd(ws_scal, red[0] + red[1] + red[2] + red[3]);
}

// ---------------- K4: new_weight = new_z_avg / w ; finalize quant_diff ----------------
__global__ void k_weight(const float* __restrict__ zavg_out, const float* __restrict__ nn_out,
                         const float* __restrict__ ws_scal, float* __restrict__ out_w,
                         float* __restrict__ out_qdiff) {
    int i = blockIdx.x * 256 + threadIdx.x;
    if (i == 0) out_qdiff[0] = ws_scal[0] * (1.0f / 8388608.0f);
    int v = i >> 8;
    float n = ws_scal[1];
    float w = (nn_out[v] + EPS_F) / (n + VEPS_F) * n;
    out_w[i] = zavg_out[i] / w;
}

extern "C" void kernel_launch(void* const* d_in, const int* in_sizes, int n_in,
                              void* d_out, int out_size, void* d_ws, size_t ws_size,
                              hipStream_t stream) {
    const float* x    = (const float*)d_in[0];
    const float* w    = (const float*)d_in[1];
    const float* N    = (const float*)d_in[2];
    const float* zavg = (const float*)d_in[3];
    float* out = (float*)d_out;
    char*  wsb = (char*)d_ws;

    // workspace layout (bytes)
    float* ws_scal   = (float*)wsb;                      // 64 B   [0]=qdiff sum [1]=n
    int*   ws_counts = (int*)(wsb + 64);                 // 32 KB
    float* ws_wnorm  = (float*)(wsb + 32832);            // 32 KB
    int*   ws_off    = (int*)(wsb + 65600);              // 32 KB
    int*   ws_cur    = (int*)(wsb + 98368);              // 32 KB
    int*   ws_bin    = (int*)(wsb + 131136);             // 128 KB
    unsigned long long* ws_best = (unsigned long long*)(wsb + 262208);  // 256 KB
    _Float16* Xh = (_Float16*)(wsb + 524352);            // 16.78 MB
    _Float16* Xl = (_Float16*)(wsb + 524352 + 16777216);
    _Float16* Wh = (_Float16*)(wsb + 524352 + 2 * 16777216);  // 4.19 MB
    _Float16* Wl = (_Float16*)(wsb + 524352 + 2 * 16777216 + 4194304);
    // total ~42.5 MB

    hipMemsetAsync(wsb, 0, 32832, stream);                       // scal + counts
    hipMemsetAsync(ws_best, 0xFF, (size_t)M_ROWS * 8, stream);

    k_split_w<<<(V_CODES * D_DIM) / (256 * 8), 256, 0, stream>>>(w, Wh, Wl, ws_wnorm);
    k_split_x<<<1024, 256, 0, stream>>>(x, Xh, Xl);

    dim3 grid(V_CODES / 256, M_ROWS / 256);
    k_mfma_argmin<<<grid, 512, 0, stream>>>(Xh, Xl, Wh, Wl, ws_wnorm, ws_best);

    k_count  <<<M_ROWS / 256, 256, 0, stream>>>(ws_best, ws_counts, out);
    k_prefix <<<1, 256, 0, stream>>>(ws_counts, ws_off, ws_cur);
    k_fill   <<<M_ROWS / 256, 256, 0, stream>>>(ws_best, ws_cur, ws_bin);
    k_codes  <<<V_CODES, 256, 0, stream>>>(Xh, Xl, N, zavg, ws_counts, ws_off, ws_bin, out, ws_scal);
    k_quant  <<<NELEM / (256 * 4), 256, 0, stream>>>(x, w, ws_best, out, ws_scal);

    k_weight <<<(V_CODES * D_DIM) / 256, 256, 0, stream>>>(out + OFF_ZAVG, out + OFF_NN, ws_scal,
                                                           out + OFF_W, out + OFF_QDIFF);
}

// Round 9
// 886.473 us; speedup vs baseline: 1.1953x; 1.1953x over previous
//
#include <hip/hip_runtime.h>

// ---------------- problem constants ----------------
#define V_CODES 8192
#define D_DIM   256
#define SPATIAL 4096            // 16*16*16
#define M_ROWS  32768           // 8 * 4096
#define NELEM   8388608         // M_ROWS * D_DIM

static constexpr float GAMMA_F = 0.99f;
static constexpr float OMG_F   = (float)(1.0 - 0.99);
static constexpr float EPS_F   = 1e-7f;
static constexpr float VEPS_F  = (float)(8192 * 1e-7);

// output layout (floats), concatenated in reference return order
static constexpr size_t OFF_QUANT = 0;            // 8388608  quant_st
static constexpr size_t OFF_IDX   = 8388608;      // 32768    enc_idx (stored as float)
static constexpr size_t OFF_QDIFF = 8421376;      // 1        quant_diff
static constexpr size_t OFF_NN    = 8421377;      // 8192     new_N
static constexpr size_t OFF_ZAVG  = 8429569;      // 2097152  new_z_avg
static constexpr size_t OFF_W     = 10526721;     // 2097152  new_weight

typedef _Float16 f16x8  __attribute__((ext_vector_type(8)));
typedef _Float16 f16x4  __attribute__((ext_vector_type(4)));
typedef float    f32x4  __attribute__((ext_vector_type(4)));

// async global->LDS, 16B per lane; LDS dest is wave-uniform base + lane*16
#define GLL(gp, lp) __builtin_amdgcn_global_load_lds( \
    (const __attribute__((address_space(1))) unsigned int*)(gp), \
    (__attribute__((address_space(3))) unsigned int*)(lp), 16, 0, 0)

// ---------------- K0c: split W into fp16 hi/lo planes + row norms (fused) ----------------
__global__ void k_split_w(const float* __restrict__ W, _Float16* __restrict__ Wh,
                          _Float16* __restrict__ Wl, float* __restrict__ wnorm) {
    int t = threadIdx.x;
    size_t i8 = ((size_t)blockIdx.x * 256 + t) * 8;
    float4 a = *(const float4*)(W + i8);
    float4 b = *(const float4*)(W + i8 + 4);
    float v[8] = {a.x, a.y, a.z, a.w, b.x, b.y, b.z, b.w};
    f16x8 hi, lo;
    float ns = 0.0f;
    #pragma unroll
    for (int j = 0; j < 8; j++) {
        _Float16 h = (_Float16)v[j];
        hi[j] = h;
        lo[j] = (_Float16)(v[j] - (float)h);
        ns = fmaf(v[j], v[j], ns);
    }
    *(f16x8*)(Wh + i8) = hi;
    *(f16x8*)(Wl + i8) = lo;
    // row norm: 32 threads per 256-elem row (8 elems each); reduce in 32-group
    #pragma unroll
    for (int m = 16; m > 0; m >>= 1) ns += __shfl_xor(ns, m, 64);
    if ((t & 31) == 0) wnorm[blockIdx.x * 8 + (t >> 5)] = ns;
}

// ---------------- K0d: split + transpose X (b,k,sp) -> Xh/Xl (m, k) row-major ----------------
__global__ void k_split_x(const float* __restrict__ X, _Float16* __restrict__ Xh,
                          _Float16* __restrict__ Xl) {
    int bid  = blockIdx.x;            // 1024 blocks
    int lane = threadIdx.x & 63;
    int kg   = (bid & 1) * 4 + (threadIdx.x >> 6);   // 0..7 -> k base kg*32
    int m    = (bid >> 1) * 64 + lane;
    int b  = m >> 12;
    int sp = m & 4095;
    const float* src = X + (size_t)b * (D_DIM * SPATIAL) + (size_t)(kg * 32) * SPATIAL + sp;
    float v[32];
    #pragma unroll
    for (int j = 0; j < 32; j++) v[j] = src[(size_t)j * SPATIAL];   // coalesced across lanes
    _Float16* dh = Xh + (size_t)m * D_DIM + kg * 32;
    _Float16* dl = Xl + (size_t)m * D_DIM + kg * 32;
    #pragma unroll
    for (int c = 0; c < 4; c++) {
        f16x8 hi, lo;
        #pragma unroll
        for (int j = 0; j < 8; j++) {
            float x = v[c * 8 + j];
            _Float16 h = (_Float16)x;
            hi[j] = h;
            lo[j] = (_Float16)(x - (float)h);
        }
        *(f16x8*)(dh + c * 8) = hi;
        *(f16x8*)(dl + c * 8) = lo;
    }
}

// ---------------- K1: MFMA distance GEMM + argmin ----------------
// v10: R7/v8's exact inner structure (128x256 tile, 4 waves 2x2, single
// 48 KiB buffer, 2 syncthreads per K-step, same fragment math & product
// order hh/lh/hl -- best measured, 539 us) wrapped in an 8-panel v-loop:
// each block sweeps v0..v0+2047 via 8 consecutive 256-wide W panels.
//  - grid 8192 -> 1024 blocks: per-block fixed costs amortized 8x (the
//    only lever that has produced wins: R7 = geometry/amortization)
//  - atomicMin writers per m: 32 -> 4 (WRITE_SIZE 65 -> ~10 MB; counter-
//    verified cost: 32768 x writers x 64 B line)
//  - bijective XCD remap: id&7 -> XCD gets one v-chunk (2 MB W working
//    set, L2-resident) + contiguous y range. 1024%8==0 -> bijective.
// LDS: 48 subtiles x 1 KiB: Xh 0-7, Xl 8-15, Wh 16-31, Wl 32-47.
// Subtile fragment order: lane l <-> halves [8l,8l+8) = row (l&15),
// k-chunk (l>>4) -> linear GLL dest, conflict-free ds_read_b128.
__device__ inline unsigned long long packkey(float s, int v) {
    unsigned u = __float_as_uint(s);
    u = (u & 0x80000000u) ? ~u : (u | 0x80000000u);
    return ((unsigned long long)u << 32) | (unsigned)v;
}

__global__ __launch_bounds__(256, 2) void k_mfma_argmin(
        const _Float16* __restrict__ Xh, const _Float16* __restrict__ Xl,
        const _Float16* __restrict__ Wh, const _Float16* __restrict__ Wl,
        const float* __restrict__ wnorm, unsigned long long* __restrict__ best) {
    __shared__ __align__(16) _Float16 lds[24576];   // 48 KiB, single buffer
    const int tid  = threadIdx.x;
    const int wid  = tid >> 6;
    const int lane = tid & 63;
    const int lrow = lane & 15, lq = lane >> 4;
    const int wy = wid >> 1, wx = wid & 1;          // wave out: rows [wy*64,+64), cols [wx*128,+128)

    // bijective XCD remap: id = bx + 4*by (HW linear); xcd c = id&7 owns
    // v-chunk x' = c>>1 and y half (c&1). Perf-only; bijection exact.
    const int id = blockIdx.x + (blockIdx.y << 2);  // gridDim = (4, 256)
    const int c  = id & 7;
    const int wi = id >> 3;                          // 0..127
    const int xp = c >> 1;                           // v-chunk 0..3
    const int yp = ((c & 1) << 7) | wi;              // 0..255
    const int m0 = yp * 128;
    const int v0_base = xp * 2048;

    const _Float16* const planes[4] = {Xh, Xl, Wh, Wl};

    // staging: wave wid owns subtiles ss = wid*12 .. wid*12+11
    // gp0: X members carry m0; W members carry row-offset only (panel adds v0p)
    const _Float16* gp0[12];
    bool isW[12];
    #pragma unroll
    for (int j = 0; j < 12; ++j) {
        int ss = wid * 12 + j;
        int pl = (ss >= 8) + (ss >= 16) + (ss >= 32);
        int ro = ss - (pl == 1 ? 8 : pl == 2 ? 16 : pl == 3 ? 32 : 0);
        isW[j] = (pl >= 2);
        gp0[j] = planes[pl] + (size_t)((pl < 2 ? m0 : 0) + ro * 16 + lrow) * D_DIM + lq * 8;
    }

    for (int p = 0; p < 8; ++p) {
        const int v0 = v0_base + p * 256;
        const _Float16* gp[12];
        #pragma unroll
        for (int j = 0; j < 12; ++j)
            gp[j] = gp0[j] + (isW[j] ? (size_t)v0 * D_DIM : 0);

        f32x4 acc[4][8];
        #pragma unroll
        for (int mi = 0; mi < 4; ++mi)
            #pragma unroll
            for (int vi = 0; vi < 8; ++vi) acc[mi][vi] = (f32x4){0.f, 0.f, 0.f, 0.f};

        for (int k0 = 0; k0 < D_DIM; k0 += 32) {
            __syncthreads();                            // prior LDS reads done
            #pragma unroll
            for (int j = 0; j < 12; ++j)
                GLL(gp[j] + k0, &lds[(wid * 12 + j) * 512]);
            __syncthreads();                            // GLL writes visible
            f16x8 ah[4], al[4];
            #pragma unroll
            for (int i = 0; i < 4; ++i) {
                ah[i] = *(const f16x8*)&lds[(     wy * 4 + i) * 512 + lane * 8];
                al[i] = *(const f16x8*)&lds[(8 +  wy * 4 + i) * 512 + lane * 8];
            }
            #pragma unroll
            for (int h = 0; h < 4; ++h) {               // vi quarter: vi = h*2+vj
                f16x8 bh[2], bl[2];
                #pragma unroll
                for (int i = 0; i < 2; ++i) {
                    bh[i] = *(const f16x8*)&lds[(16 + wx * 8 + h * 2 + i) * 512 + lane * 8];
                    bl[i] = *(const f16x8*)&lds[(32 + wx * 8 + h * 2 + i) * 512 + lane * 8];
                }
                __builtin_amdgcn_s_setprio(1);
                #pragma unroll
                for (int mi = 0; mi < 4; ++mi)
                    #pragma unroll
                    for (int vj = 0; vj < 2; ++vj) {
                        acc[mi][h*2+vj] = __builtin_amdgcn_mfma_f32_16x16x32_f16(ah[mi], bh[vj], acc[mi][h*2+vj], 0, 0, 0);
                        acc[mi][h*2+vj] = __builtin_amdgcn_mfma_f32_16x16x32_f16(al[mi], bh[vj], acc[mi][h*2+vj], 0, 0, 0);
                        acc[mi][h*2+vj] = __builtin_amdgcn_mfma_f32_16x16x32_f16(ah[mi], bl[vj], acc[mi][h*2+vj], 0, 0, 0);
                    }
                __builtin_amdgcn_s_setprio(0);
            }
        }

        float wnv[8];
        #pragma unroll
        for (int vi = 0; vi < 8; ++vi) wnv[vi] = wnorm[v0 + (wx * 8 + vi) * 16 + lrow];

        #pragma unroll
        for (int mi = 0; mi < 4; ++mi) {
            #pragma unroll
            for (int r = 0; r < 4; ++r) {
                unsigned long long k = ~0ull;
                #pragma unroll
                for (int vi = 0; vi < 8; ++vi) {
                    int v = v0 + (wx * 8 + vi) * 16 + lrow;
                    float s = wnv[vi] - 2.0f * acc[mi][vi][r];
                    unsigned long long key = packkey(s, v);
                    k = key < k ? key : k;
                }
                #pragma unroll
                for (int msk = 1; msk < 16; msk <<= 1) {
                    unsigned long long o = __shfl_xor(k, msk, 64);
                    k = o < k ? o : k;
                }
                if (lrow == 0) {
                    int m = m0 + (wy * 4 + mi) * 16 + lq * 4 + r;
                    atomicMin(&best[m], k);
                }
            }
        }
    }
}

// ---------------- K2a: extract idx, count per code ----------------
__global__ void k_count(const unsigned long long* __restrict__ best,
                        int* __restrict__ counts, float* __restrict__ out) {
    int m = blockIdx.x * 256 + threadIdx.x;
    int v = (int)(unsigned)(best[m] & 0xFFFFFFFFull);
    atomicAdd(&counts[v], 1);
    out[OFF_IDX + m] = (float)v;
}

// ---------------- K2b: exclusive prefix over 8192 counts ----------------
__global__ void k_prefix(const int* __restrict__ counts, int* __restrict__ offsets,
                         int* __restrict__ cursor) {
    __shared__ int tsum[256];
    int t = threadIdx.x;
    int local[32];
    int s = 0;
    #pragma unroll
    for (int i = 0; i < 32; i++) { local[i] = s; s += counts[t * 32 + i]; }
    tsum[t] = s;
    __syncthreads();
    if (t == 0) {
        int run = 0;
        for (int i = 0; i < 256; i++) { int c = tsum[i]; tsum[i] = run; run += c; }
    }
    __syncthreads();
    int base = tsum[t];
    #pragma unroll
    for (int i = 0; i < 32; i++) {
        int o = base + local[i];
        offsets[t * 32 + i] = o;
        cursor[t * 32 + i]  = o;
    }
}

// ---------------- K2c: fill bins ----------------
__global__ void k_fill(const unsigned long long* __restrict__ best,
                       int* __restrict__ cursor, int* __restrict__ bin) {
    int m = blockIdx.x * 256 + threadIdx.x;
    int v = (int)(unsigned)(best[m] & 0xFFFFFFFFull);
    int pos = atomicAdd(&cursor[v], 1);
    bin[pos] = m;
}

// ---------------- K2d: per-code reduction -> new_N, new_z_avg ----------------
__global__ void k_codes(const _Float16* __restrict__ Xh, const _Float16* __restrict__ Xl,
                        const float* __restrict__ N, const float* __restrict__ zavg,
                        const int* __restrict__ counts, const int* __restrict__ offsets,
                        const int* __restrict__ bin, float* __restrict__ out,
                        float* __restrict__ ws_scal) {
    int v = blockIdx.x;
    int t = threadIdx.x;
    int r4 = t >> 6;          // row class 0..3
    int dg = t & 63;          // d-group: d = dg*4 .. dg*4+3
    int cnt = counts[v];
    int off = offsets[v];
    float s0 = 0.f, s1 = 0.f, s2 = 0.f, s3 = 0.f;
    for (int r = r4; r < cnt; r += 4) {
        int m = bin[off + r];
        f16x4 h = *(const f16x4*)(Xh + (size_t)m * D_DIM + dg * 4);
        f16x4 l = *(const f16x4*)(Xl + (size_t)m * D_DIM + dg * 4);
        s0 += (float)h[0] + (float)l[0];
        s1 += (float)h[1] + (float)l[1];
        s2 += (float)h[2] + (float)l[2];
        s3 += (float)h[3] + (float)l[3];
    }
    __shared__ float red[4][256];
    *(float4*)&red[r4][dg * 4] = make_float4(s0, s1, s2, s3);
    __syncthreads();
    float tot = red[0][t] + red[1][t] + red[2][t] + red[3][t];
    out[OFF_ZAVG + (size_t)v * D_DIM + t] = GAMMA_F * zavg[(size_t)v * D_DIM + t] + OMG_F * tot;
    if (t == 0) {
        float nn = GAMMA_F * N[v] + OMG_F * (float)cnt;
        out[OFF_NN + v] = nn;
        atomicAdd(&ws_scal[1], nn);
    }
}

// ---------------- K3: quant_st + quant_diff (float4 along sp) ----------------
__global__ void k_quant(const float* __restrict__ X, const float* __restrict__ W,
                        const unsigned long long* __restrict__ best, float* __restrict__ out,
                        float* __restrict__ ws_scal) {
    int e4 = blockIdx.x * 256 + threadIdx.x;    // element/4 in (b, d, sp) order
    int e  = e4 * 4;
    int sp = e & 4095;
    int bd = e >> 12;
    int d  = bd & 255;
    int b  = bd >> 8;
    int mb = b * SPATIAL + sp;
    float4 x4 = *(const float4*)(X + e);
    float q[4];
    float p = 0.0f;
    #pragma unroll
    for (int j = 0; j < 4; j++) {
        int v = (int)(unsigned)(best[mb + j] & 0xFFFFFFFFull);
        float wv = W[(size_t)v * D_DIM + d];
        float xv = (j == 0) ? x4.x : (j == 1) ? x4.y : (j == 2) ? x4.z : x4.w;
        q[j] = (wv - xv) + xv;                 // straight-through
        float df = xv - wv;
        p = fmaf(df, df, p);
    }
    *(float4*)(out + OFF_QUANT + e) = make_float4(q[0], q[1], q[2], q[3]);
    // block-reduce p -> one atomic
    #pragma unroll
    for (int msk = 32; msk > 0; msk >>= 1) p += __shfl_xor(p, msk, 64);
    __shared__ float red[4];
    int lane = threadIdx.x & 63, w = threadIdx.x >> 6;
    if (lane == 0) red[w] = p;
    __syncthreads();
    if (threadIdx.x == 0)
        atomicAdd(ws_scal, red[0] + red[1] + red[2] + red[3]);
}

// ---------------- K4: new_weight = new_z_avg / w ; finalize quant_diff ----------------
__global__ void k_weight(const float* __restrict__ zavg_out, const float* __restrict__ nn_out,
                         const float* __restrict__ ws_scal, float* __restrict__ out_w,
                         float* __restrict__ out_qdiff) {
    int i = blockIdx.x * 256 + threadIdx.x;
    if (i == 0) out_qdiff[0] = ws_scal[0] * (1.0f / 8388608.0f);
    int v = i >> 8;
    float n = ws_scal[1];
    float w = (nn_out[v] + EPS_F) / (n + VEPS_F) * n;
    out_w[i] = zavg_out[i] / w;
}

extern "C" void kernel_launch(void* const* d_in, const int* in_sizes, int n_in,
                              void* d_out, int out_size, void* d_ws, size_t ws_size,
                              hipStream_t stream) {
    const float* x    = (const float*)d_in[0];
    const float* w    = (const float*)d_in[1];
    const float* N    = (const float*)d_in[2];
    const float* zavg = (const float*)d_in[3];
    float* out = (float*)d_out;
    char*  wsb = (char*)d_ws;

    // workspace layout (bytes)
    float* ws_scal   = (float*)wsb;                      // 64 B   [0]=qdiff sum [1]=n
    int*   ws_counts = (int*)(wsb + 64);                 // 32 KB
    float* ws_wnorm  = (float*)(wsb + 32832);            // 32 KB
    int*   ws_off    = (int*)(wsb + 65600);              // 32 KB
    int*   ws_cur    = (int*)(wsb + 98368);              // 32 KB
    int*   ws_bin    = (int*)(wsb + 131136);             // 128 KB
    unsigned long long* ws_best = (unsigned long long*)(wsb + 262208);  // 256 KB
    _Float16* Xh = (_Float16*)(wsb + 524352);            // 16.78 MB
    _Float16* Xl = (_Float16*)(wsb + 524352 + 16777216);
    _Float16* Wh = (_Float16*)(wsb + 524352 + 2 * 16777216);  // 4.19 MB
    _Float16* Wl = (_Float16*)(wsb + 524352 + 2 * 16777216 + 4194304);
    // total ~42.5 MB

    hipMemsetAsync(wsb, 0, 32832, stream);                       // scal + counts
    hipMemsetAsync(ws_best, 0xFF, (size_t)M_ROWS * 8, stream);

    k_split_w<<<(V_CODES * D_DIM) / (256 * 8), 256, 0, stream>>>(w, Wh, Wl, ws_wnorm);
    k_split_x<<<1024, 256, 0, stream>>>(x, Xh, Xl);

    dim3 grid(4, 256);   // 4 v-chunks (x 8 panels inside) x 256 m-bands
    k_mfma_argmin<<<grid, 256, 0, stream>>>(Xh, Xl, Wh, Wl, ws_wnorm, ws_best);

    k_count  <<<M_ROWS / 256, 256, 0, stream>>>(ws_best, ws_counts, out);
    k_prefix <<<1, 256, 0, stream>>>(ws_counts, ws_off, ws_cur);
    k_fill   <<<M_ROWS / 256, 256, 0, stream>>>(ws_best, ws_cur, ws_bin);
    k_codes  <<<V_CODES, 256, 0, stream>>>(Xh, Xl, N, zavg, ws_counts, ws_off, ws_bin, out, ws_scal);
    k_quant  <<<NELEM / (256 * 4), 256, 0, stream>>>(x, w, ws_best, out, ws_scal);

    k_weight <<<(V_CODES * D_DIM) / 256, 256, 0, stream>>>(out + OFF_ZAVG, out + OFF_NN, ws_scal,
                                                           out + OFF_W, out + OFF_QDIFF);
}

// Round 10
// 804.268 us; speedup vs baseline: 1.3175x; 1.1022x over previous
//
#include <hip/hip_runtime.h>

// ---------------- problem constants ----------------
#define V_CODES 8192
#define D_DIM   256
#define SPATIAL 4096            // 16*16*16
#define M_ROWS  32768           // 8 * 4096
#define NELEM   8388608         // M_ROWS * D_DIM

static constexpr float GAMMA_F = 0.99f;
static constexpr float OMG_F   = (float)(1.0 - 0.99);
static constexpr float EPS_F   = 1e-7f;
static constexpr float VEPS_F  = (float)(8192 * 1e-7);

// output layout (floats), concatenated in reference return order
static constexpr size_t OFF_QUANT = 0;            // 8388608  quant_st
static constexpr size_t OFF_IDX   = 8388608;      // 32768    enc_idx (stored as float)
static constexpr size_t OFF_QDIFF = 8421376;      // 1        quant_diff
static constexpr size_t OFF_NN    = 8421377;      // 8192     new_N
static constexpr size_t OFF_ZAVG  = 8429569;      // 2097152  new_z_avg
static constexpr size_t OFF_W     = 10526721;     // 2097152  new_weight

typedef _Float16 f16x8  __attribute__((ext_vector_type(8)));
typedef _Float16 f16x4  __attribute__((ext_vector_type(4)));
typedef float    f32x4  __attribute__((ext_vector_type(4)));

// async global->LDS, 16B per lane; LDS dest is wave-uniform base + lane*16
#define GLL(gp, lp) __builtin_amdgcn_global_load_lds( \
    (const __attribute__((address_space(1))) unsigned int*)(gp), \
    (__attribute__((address_space(3))) unsigned int*)(lp), 16, 0, 0)

// ---------------- K0: fused W-split(+norms) and X-split (one launch) ----------------
__global__ void k_split(const float* __restrict__ W, _Float16* __restrict__ Wh,
                        _Float16* __restrict__ Wl, float* __restrict__ wnorm,
                        const float* __restrict__ X, _Float16* __restrict__ Xh,
                        _Float16* __restrict__ Xl) {
    if (blockIdx.x < 1024) {
        // ---- W split + row norms (1024 blocks) ----
        int t = threadIdx.x;
        size_t i8 = ((size_t)blockIdx.x * 256 + t) * 8;
        float4 a = *(const float4*)(W + i8);
        float4 b = *(const float4*)(W + i8 + 4);
        float v[8] = {a.x, a.y, a.z, a.w, b.x, b.y, b.z, b.w};
        f16x8 hi, lo;
        float ns = 0.0f;
        #pragma unroll
        for (int j = 0; j < 8; j++) {
            _Float16 h = (_Float16)v[j];
            hi[j] = h;
            lo[j] = (_Float16)(v[j] - (float)h);
            ns = fmaf(v[j], v[j], ns);
        }
        *(f16x8*)(Wh + i8) = hi;
        *(f16x8*)(Wl + i8) = lo;
        #pragma unroll
        for (int m = 16; m > 0; m >>= 1) ns += __shfl_xor(ns, m, 64);
        if ((t & 31) == 0) wnorm[blockIdx.x * 8 + (t >> 5)] = ns;
    } else {
        // ---- X split + transpose (1024 blocks) ----
        int bid  = blockIdx.x - 1024;
        int lane = threadIdx.x & 63;
        int kg   = (bid & 1) * 4 + (threadIdx.x >> 6);   // 0..7 -> k base kg*32
        int m    = (bid >> 1) * 64 + lane;
        int b  = m >> 12;
        int sp = m & 4095;
        const float* src = X + (size_t)b * (D_DIM * SPATIAL) + (size_t)(kg * 32) * SPATIAL + sp;
        float v[32];
        #pragma unroll
        for (int j = 0; j < 32; j++) v[j] = src[(size_t)j * SPATIAL];   // coalesced across lanes
        _Float16* dh = Xh + (size_t)m * D_DIM + kg * 32;
        _Float16* dl = Xl + (size_t)m * D_DIM + kg * 32;
        #pragma unroll
        for (int c = 0; c < 4; c++) {
            f16x8 hi, lo;
            #pragma unroll
            for (int j = 0; j < 8; j++) {
                float x = v[c * 8 + j];
                _Float16 h = (_Float16)x;
                hi[j] = h;
                lo[j] = (_Float16)(x - (float)h);
            }
            *(f16x8*)(dh + c * 8) = hi;
            *(f16x8*)(dl + c * 8) = lo;
        }
    }
}

// ---------------- K1: MFMA distance GEMM + argmin ----------------
// v8/R7 VERBATIM (best measured: 539 us, MfmaUtil 34%): 128x256 tile,
// 4 waves 2x2, single 48 KiB buffer, 2 syncthreads per K-step.
// LDS: 48 subtiles x 1 KiB: Xh 0-7, Xl 8-15, Wh 16-31, Wl 32-47.
// Subtile fragment order: lane l <-> halves [8l,8l+8) = row (l&15),
// k-chunk (l>>4) -> linear GLL dest, conflict-free ds_read_b128.
__device__ inline unsigned long long packkey(float s, int v) {
    unsigned u = __float_as_uint(s);
    u = (u & 0x80000000u) ? ~u : (u | 0x80000000u);
    return ((unsigned long long)u << 32) | (unsigned)v;
}

__global__ __launch_bounds__(256, 2) void k_mfma_argmin(
        const _Float16* __restrict__ Xh, const _Float16* __restrict__ Xl,
        const _Float16* __restrict__ Wh, const _Float16* __restrict__ Wl,
        const float* __restrict__ wnorm, unsigned long long* __restrict__ best) {
    __shared__ __align__(16) _Float16 lds[24576];   // 48 KiB, single buffer
    const int tid  = threadIdx.x;
    const int wid  = tid >> 6;
    const int lane = tid & 63;
    const int lrow = lane & 15, lq = lane >> 4;
    const int wy = wid >> 1, wx = wid & 1;          // wave out: rows [wy*64,+64), cols [wx*128,+128)
    const int m0 = blockIdx.y * 128;
    const int v0 = blockIdx.x * 256;

    const _Float16* const planes[4] = {Xh, Xl, Wh, Wl};

    // staging: wave wid owns subtiles ss = wid*12 .. wid*12+11
    const _Float16* gp[12];
    #pragma unroll
    for (int j = 0; j < 12; ++j) {
        int ss = wid * 12 + j;
        int pl = (ss >= 8) + (ss >= 16) + (ss >= 32);
        int ro = ss - (pl == 1 ? 8 : pl == 2 ? 16 : pl == 3 ? 32 : 0);
        gp[j] = planes[pl] + (size_t)((pl < 2 ? m0 : v0) + ro * 16 + lrow) * D_DIM + lq * 8;
    }

    f32x4 acc[4][8] = {};

    for (int k0 = 0; k0 < D_DIM; k0 += 32) {
        __syncthreads();                            // prior LDS reads done
        #pragma unroll
        for (int j = 0; j < 12; ++j)
            GLL(gp[j] + k0, &lds[(wid * 12 + j) * 512]);
        __syncthreads();                            // GLL writes visible
        f16x8 ah[4], al[4];
        #pragma unroll
        for (int i = 0; i < 4; ++i) {
            ah[i] = *(const f16x8*)&lds[(     wy * 4 + i) * 512 + lane * 8];
            al[i] = *(const f16x8*)&lds[(8 +  wy * 4 + i) * 512 + lane * 8];
        }
        #pragma unroll
        for (int h = 0; h < 4; ++h) {               // vi quarter: vi = h*2+vj
            f16x8 bh[2], bl[2];
            #pragma unroll
            for (int i = 0; i < 2; ++i) {
                bh[i] = *(const f16x8*)&lds[(16 + wx * 8 + h * 2 + i) * 512 + lane * 8];
                bl[i] = *(const f16x8*)&lds[(32 + wx * 8 + h * 2 + i) * 512 + lane * 8];
            }
            __builtin_amdgcn_s_setprio(1);
            #pragma unroll
            for (int mi = 0; mi < 4; ++mi)
                #pragma unroll
                for (int vj = 0; vj < 2; ++vj) {
                    acc[mi][h*2+vj] = __builtin_amdgcn_mfma_f32_16x16x32_f16(ah[mi], bh[vj], acc[mi][h*2+vj], 0, 0, 0);
                    acc[mi][h*2+vj] = __builtin_amdgcn_mfma_f32_16x16x32_f16(al[mi], bh[vj], acc[mi][h*2+vj], 0, 0, 0);
                    acc[mi][h*2+vj] = __builtin_amdgcn_mfma_f32_16x16x32_f16(ah[mi], bl[vj], acc[mi][h*2+vj], 0, 0, 0);
                }
            __builtin_amdgcn_s_setprio(0);
        }
    }

    float wnv[8];
    #pragma unroll
    for (int vi = 0; vi < 8; ++vi) wnv[vi] = wnorm[v0 + (wx * 8 + vi) * 16 + lrow];

    #pragma unroll
    for (int mi = 0; mi < 4; ++mi) {
        #pragma unroll
        for (int r = 0; r < 4; ++r) {
            unsigned long long k = ~0ull;
            #pragma unroll
            for (int vi = 0; vi < 8; ++vi) {
                int v = v0 + (wx * 8 + vi) * 16 + lrow;
                float s = wnv[vi] - 2.0f * acc[mi][vi][r];
                unsigned long long key = packkey(s, v);
                k = key < k ? key : k;
            }
            #pragma unroll
            for (int msk = 1; msk < 16; msk <<= 1) {
                unsigned long long o = __shfl_xor(k, msk, 64);
                k = o < k ? o : k;
            }
            if (lrow == 0) {
                int m = m0 + (wy * 4 + mi) * 16 + lq * 4 + r;
                atomicMin(&best[m], k);
            }
        }
    }
}

// ---------------- K2a: extract idx, count per code ----------------
__global__ void k_count(const unsigned long long* __restrict__ best,
                        int* __restrict__ counts, float* __restrict__ out) {
    int m = blockIdx.x * 256 + threadIdx.x;
    int v = (int)(unsigned)(best[m] & 0xFFFFFFFFull);
    atomicAdd(&counts[v], 1);
    out[OFF_IDX + m] = (float)v;
}

// ---------------- K2b: exclusive prefix over 8192 counts ----------------
__global__ void k_prefix(const int* __restrict__ counts, int* __restrict__ offsets,
                         int* __restrict__ cursor) {
    __shared__ int tsum[256];
    int t = threadIdx.x;
    int local[32];
    int s = 0;
    #pragma unroll
    for (int i = 0; i < 32; i++) { local[i] = s; s += counts[t * 32 + i]; }
    tsum[t] = s;
    __syncthreads();
    if (t == 0) {
        int run = 0;
        for (int i = 0; i < 256; i++) { int c = tsum[i]; tsum[i] = run; run += c; }
    }
    __syncthreads();
    int base = tsum[t];
    #pragma unroll
    for (int i = 0; i < 32; i++) {
        int o = base + local[i];
        offsets[t * 32 + i] = o;
        cursor[t * 32 + i]  = o;
    }
}

// ---------------- K2c: fill bins ----------------
__global__ void k_fill(const unsigned long long* __restrict__ best,
                       int* __restrict__ cursor, int* __restrict__ bin) {
    int m = blockIdx.x * 256 + threadIdx.x;
    int v = (int)(unsigned)(best[m] & 0xFFFFFFFFull);
    int pos = atomicAdd(&cursor[v], 1);
    bin[pos] = m;
}

// ---------------- K2d: per-code reduction -> new_N, new_z_avg ----------------
__global__ void k_codes(const _Float16* __restrict__ Xh, const _Float16* __restrict__ Xl,
                        const float* __restrict__ N, const float* __restrict__ zavg,
                        const int* __restrict__ counts, const int* __restrict__ offsets,
                        const int* __restrict__ bin, float* __restrict__ out,
                        float* __restrict__ ws_scal) {
    int v = blockIdx.x;
    int t = threadIdx.x;
    int r4 = t >> 6;          // row class 0..3
    int dg = t & 63;          // d-group: d = dg*4 .. dg*4+3
    int cnt = counts[v];
    int off = offsets[v];
    float s0 = 0.f, s1 = 0.f, s2 = 0.f, s3 = 0.f;
    for (int r = r4; r < cnt; r += 4) {
        int m = bin[off + r];
        f16x4 h = *(const f16x4*)(Xh + (size_t)m * D_DIM + dg * 4);
        f16x4 l = *(const f16x4*)(Xl + (size_t)m * D_DIM + dg * 4);
        s0 += (float)h[0] + (float)l[0];
        s1 += (float)h[1] + (float)l[1];
        s2 += (float)h[2] + (float)l[2];
        s3 += (float)h[3] + (float)l[3];
    }
    __shared__ float red[4][256];
    *(float4*)&red[r4][dg * 4] = make_float4(s0, s1, s2, s3);
    __syncthreads();
    float tot = red[0][t] + red[1][t] + red[2][t] + red[3][t];
    out[OFF_ZAVG + (size_t)v * D_DIM + t] = GAMMA_F * zavg[(size_t)v * D_DIM + t] + OMG_F * tot;
    if (t == 0) {
        float nn = GAMMA_F * N[v] + OMG_F * (float)cnt;
        out[OFF_NN + v] = nn;
        atomicAdd(&ws_scal[1], nn);
    }
}

// ---------------- K3: quant_st + quant_diff -- m-major, W rows via LDS ----------------
// v11: eliminates the scattered 4B W[v][d] gather. Each block owns 64 rows
// (one b, 64 consecutive sp): reads best once, stages the 64 indexed W rows
// into LDS coalescedly, then streams all 256 d's. Out/X accesses are 256 B
// contiguous per wave (lane = sp). LDS row pad 258 floats -> worst 4-way
// read conflict (1.58x, off critical path). ~66 KiB LDS -> 2 blocks/CU.
__global__ __launch_bounds__(256, 2) void k_quant(
        const float* __restrict__ X, const float* __restrict__ W,
        const unsigned long long* __restrict__ best, float* __restrict__ out,
        float* __restrict__ ws_scal) {
    __shared__ float wrow[64][258];
    __shared__ int   vbuf[64];
    __shared__ float red[4];
    const int t  = threadIdx.x;
    const int m0 = blockIdx.x * 64;          // 512 blocks
    const int b  = m0 >> 12;
    const int spb = m0 & 4095;

    if (t < 64) vbuf[t] = (int)(unsigned)(best[m0 + t] & 0xFFFFFFFFull);
    __syncthreads();

    {   // stage 64 W rows: thread t -> row r=t>>2, quarter q=t&3 (64 d via float2)
        const int r = t >> 2, q = t & 3;
        const float* src = W + (size_t)vbuf[r] * D_DIM + q * 64;
        #pragma unroll
        for (int i = 0; i < 32; ++i) {
            float2 w2 = *(const float2*)(src + i * 2);
            wrow[r][q * 64 + i * 2]     = w2.x;
            wrow[r][q * 64 + i * 2 + 1] = w2.y;
        }
    }
    __syncthreads();

    // stream: thread t -> sp index si=t&63, d quarter dq=t>>6
    const int si = t & 63, dq = t >> 6;
    const size_t xbase = (size_t)b * (D_DIM * SPATIAL) + spb + si;
    float p = 0.0f;
    #pragma unroll 8
    for (int dd = 0; dd < 64; ++dd) {
        const int d = dq * 64 + dd;
        const size_t idx = xbase + (size_t)d * SPATIAL;
        float xv = X[idx];
        float wv = wrow[si][d];
        out[OFF_QUANT + idx] = (wv - xv) + xv;   // straight-through
        float df = xv - wv;
        p = fmaf(df, df, p);
    }
    // block-reduce p -> one atomic
    #pragma unroll
    for (int msk = 32; msk > 0; msk >>= 1) p += __shfl_xor(p, msk, 64);
    const int lane = t & 63, w = t >> 6;
    if (lane == 0) red[w] = p;
    __syncthreads();
    if (t == 0)
        atomicAdd(ws_scal, red[0] + red[1] + red[2] + red[3]);
}

// ---------------- K4: new_weight = new_z_avg / w ; finalize quant_diff ----------------
__global__ void k_weight(const float* __restrict__ zavg_out, const float* __restrict__ nn_out,
                         const float* __restrict__ ws_scal, float* __restrict__ out_w,
                         float* __restrict__ out_qdiff) {
    int i = blockIdx.x * 256 + threadIdx.x;
    if (i == 0) out_qdiff[0] = ws_scal[0] * (1.0f / 8388608.0f);
    int v = i >> 8;
    float n = ws_scal[1];
    float w = (nn_out[v] + EPS_F) / (n + VEPS_F) * n;
    out_w[i] = zavg_out[i] / w;
}

extern "C" void kernel_launch(void* const* d_in, const int* in_sizes, int n_in,
                              void* d_out, int out_size, void* d_ws, size_t ws_size,
                              hipStream_t stream) {
    const float* x    = (const float*)d_in[0];
    const float* w    = (const float*)d_in[1];
    const float* N    = (const float*)d_in[2];
    const float* zavg = (const float*)d_in[3];
    float* out = (float*)d_out;
    char*  wsb = (char*)d_ws;

    // workspace layout (bytes)
    float* ws_scal   = (float*)wsb;                      // 64 B   [0]=qdiff sum [1]=n
    int*   ws_counts = (int*)(wsb + 64);                 // 32 KB
    float* ws_wnorm  = (float*)(wsb + 32832);            // 32 KB
    int*   ws_off    = (int*)(wsb + 65600);              // 32 KB
    int*   ws_cur    = (int*)(wsb + 98368);              // 32 KB
    int*   ws_bin    = (int*)(wsb + 131136);             // 128 KB
    unsigned long long* ws_best = (unsigned long long*)(wsb + 262208);  // 256 KB
    _Float16* Xh = (_Float16*)(wsb + 524352);            // 16.78 MB
    _Float16* Xl = (_Float16*)(wsb + 524352 + 16777216);
    _Float16* Wh = (_Float16*)(wsb + 524352 + 2 * 16777216);  // 4.19 MB
    _Float16* Wl = (_Float16*)(wsb + 524352 + 2 * 16777216 + 4194304);
    // total ~42.5 MB

    hipMemsetAsync(wsb, 0, 32832, stream);                       // scal + counts
    hipMemsetAsync(ws_best, 0xFF, (size_t)M_ROWS * 8, stream);

    k_split<<<2048, 256, 0, stream>>>(w, Wh, Wl, ws_wnorm, x, Xh, Xl);

    dim3 grid(V_CODES / 256, M_ROWS / 128);
    k_mfma_argmin<<<grid, 256, 0, stream>>>(Xh, Xl, Wh, Wl, ws_wnorm, ws_best);

    k_count  <<<M_ROWS / 256, 256, 0, stream>>>(ws_best, ws_counts, out);
    k_prefix <<<1, 256, 0, stream>>>(ws_counts, ws_off, ws_cur);
    k_fill   <<<M_ROWS / 256, 256, 0, stream>>>(ws_best, ws_cur, ws_bin);
    k_codes  <<<V_CODES, 256, 0, stream>>>(Xh, Xl, N, zavg, ws_counts, ws_off, ws_bin, out, ws_scal);
    k_quant  <<<M_ROWS / 64, 256, 0, stream>>>(x, w, ws_best, out, ws_scal);

    k_weight <<<(V_CODES * D_DIM) / 256, 256, 0, stream>>>(out + OFF_ZAVG, out + OFF_NN, ws_scal,
                                                           out + OFF_W, out + OFF_QDIFF);
}